// Round 17
// baseline (164.303 us; speedup 1.0000x reference)
//
#include <hip/hip_runtime.h>
#include <hip/hip_bf16.h>
#include <math.h>

#define F_N 5
#define K_N 6
#define T_N 12
#define M_N 3600
#define S_N 400
#define R_N 16
#define B_N 128

#define PI_F 3.14159265358979f
#define CLIP_HI 0.3490658503988659f
#define NEG_TWO_PI_OVER_C (-6.283185307179586f / 3.0e8f)
#define INV_TWO_PI 0.15915494309189535f

#define SA_BASE   0         // s_A  [11520][400] float32
#define MIC_BASE  4608000   // s_mic [11520][128] float32

#define NK 113              // K-chunks of 32 (113*32 = 3616 >= 3600)
#define KP (NK * 32)
#define W_ELEMS  (5 * 48 * KP)        // 867,840 bf16   W2[f][kk][48][32]
#define C_ELEMS  (4 * 5 * 48 * 800)   // 768,000 f32 (split-K=4 partials)
#define WS_NEED  ((size_t)W_ELEMS * 2 + (size_t)C_ELEMS * 4)

typedef __attribute__((ext_vector_type(8))) short bf16x8;
typedef __attribute__((ext_vector_type(4))) float f32x4;

// Hardware sin/cos (v_sin_f32/v_cos_f32 take REVOLUTIONS; fract first).
__device__ __forceinline__ void fast_sincos(float x, float* s, float* c) {
    float r = x * INV_TWO_PI;
    r -= floorf(r);
    *s = __builtin_amdgcn_sinf(r);
    *c = __builtin_amdgcn_cosf(r);
}

__device__ __forceinline__ ushort f2bf(float v) {
    __hip_bfloat16 h = __float2bfloat16(v);
    union { __hip_bfloat16 h; ushort u; } cv; cv.h = h;
    return cv.u;
}

// ---------------- MFMA path ----------------
// W2[f][kk][row48][32]  row: 0..5 Re(A1 k), 6..21 Re(H4p r),
//                            22..27 Im(A1 k), 28..43 Im(H4p r), 44..47 zero
// H (B operand) is GENERATED IN-REGISTER inside gemm (never materialized):
// B row n: n<400 -> amp*cos (Re H2[:,s=n]); n>=400 -> amp*sin (Im, s=n-400).

__global__ __launch_bounds__(256) void stage_kernel(
    const float* __restrict__ w, const float* __restrict__ meta_theta,
    const float* __restrict__ fin, const float* __restrict__ txp,
    const float* __restrict__ rxp, const float* __restrict__ metap,
    __hip_bfloat16* __restrict__ Wbf)
{
    __shared__ float pri[K_N * T_N * 2];
    __shared__ float txs[T_N * 3];
    __shared__ float rxs[R_N * 3];
    const int tid = threadIdx.x;
    const int f = blockIdx.x / 15;
    const int mblk = blockIdx.x % 15;

    if (tid < K_N * T_N) {
        float sv, cv; fast_sincos(w[f * (K_N * T_N) + tid], &sv, &cv);
        pri[tid * 2] = cv; pri[tid * 2 + 1] = sv;
    }
    if (tid >= 64 && tid < 64 + T_N * 3) txs[tid - 64] = txp[tid - 64];
    if (tid >= 128 && tid < 128 + R_N * 3) rxs[tid - 128] = rxp[tid - 128];
    __syncthreads();

    const int m = mblk * 256 + tid;
    if (m >= KP) return;
    __hip_bfloat16* wb = Wbf + ((size_t)(f * NK + (m >> 5)) * 48) * 32 + (m & 31);

    if (m >= M_N) {                   // K padding columns
        for (int row = 0; row < 48; ++row) wb[row * 32] = __float2bfloat16(0.f);
        return;
    }

    const float px = metap[m * 3 + 0];
    const float py = metap[m * 3 + 1];
    const float pz = metap[m * 3 + 2];
    const float coef = NEG_TWO_PI_OVER_C * fin[f];

    float th = meta_theta[m];
    th = fminf(fmaxf(th, -PI_F), CLIP_HI);
    float phs, phc; fast_sincos(th, &phs, &phc);

    float hre[T_N], him[T_N];
#pragma unroll
    for (int t = 0; t < T_N; ++t) {
        float dx = txs[t * 3 + 0] - px, dy = txs[t * 3 + 1] - py, dz = txs[t * 3 + 2] - pz;
        float d = sqrtf(dx * dx + dy * dy + dz * dz);
        float amp = 1e-3f / (d * d);
        float sv, cv; fast_sincos(coef * d, &sv, &cv);
        hre[t] = amp * cv; him[t] = amp * sv;
    }
#pragma unroll
    for (int k = 0; k < K_N; ++k) {
        float ar = 0.f, ai = 0.f;
#pragma unroll
        for (int t = 0; t < T_N; ++t) {
            float pr = pri[(k * T_N + t) * 2], pim = pri[(k * T_N + t) * 2 + 1];
            ar += pr * hre[t] - pim * him[t];
            ai += pr * him[t] + pim * hre[t];
        }
        wb[k * 32]        = __float2bfloat16(ar * phc - ai * phs);
        wb[(22 + k) * 32] = __float2bfloat16(ar * phs + ai * phc);
    }
#pragma unroll
    for (int r = 0; r < R_N; ++r) {
        float dx = rxs[r * 3 + 0] - px, dy = rxs[r * 3 + 1] - py, dz = rxs[r * 3 + 2] - pz;
        float d = sqrtf(dx * dx + dy * dy + dz * dz);
        float amp = 1e-3f / (d * d);
        float sv, cv; fast_sincos(coef * d, &sv, &cv);
        float cr = amp * cv, ci = amp * sv;
        wb[(6 + r) * 32]  = __float2bfloat16(cr * phc - ci * phs);
        wb[(28 + r) * 32] = __float2bfloat16(cr * phs + ci * phc);
    }
#pragma unroll
    for (int row = 44; row < 48; ++row) wb[row * 32] = __float2bfloat16(0.f);
}

// [48 x KP] x [KP x 800] bf16 MFMA GEMM per f, split-K=4 partials.
// B fragments generated in-register (8 sin-or-cos per lane per k-chunk).
__global__ __launch_bounds__(128) void gemm_kernel(
    const ushort* __restrict__ Wbf, const float* __restrict__ fin,
    const float* __restrict__ metap, const float* __restrict__ scenep,
    float* __restrict__ Cp)
{
    const int blk = blockIdx.x;           // 5 * 25 * 4 = 500
    const int f = blk / 100;
    const int rem = blk % 100;
    const int nblk = rem / 4;
    const int ksp = rem % 4;
    const int wave = threadIdx.x >> 6;
    const int lane = threadIdx.x & 63;
    const int quad = lane >> 4;
    const int l16 = lane & 15;

    const int n = nblk * 32 + wave * 16 + l16;      // < 800
    const int isIm = (n >= 400);
    const int s = isIm ? (n - 400) : n;
    const int kbeg = (ksp == 0) ? 0 : (29 + 28 * (ksp - 1));
    const int kcnt = (ksp == 0) ? 29 : 28;          // 29+28*3 == 113

    const float coef = NEG_TWO_PI_OVER_C * fin[f];
    const float sx = scenep[s * 3 + 0];
    const float sy = scenep[s * 3 + 1];
    const float sz = scenep[s * 3 + 2];

    f32x4 acc0 = {0.f, 0.f, 0.f, 0.f};
    f32x4 acc1 = {0.f, 0.f, 0.f, 0.f};
    f32x4 acc2 = {0.f, 0.f, 0.f, 0.f};

    for (int kk = 0; kk < kcnt; ++kk) {
        const int kb = kbeg + kk;
        const int m0 = kb * 32 + quad * 8;

        union { ushort u[8]; bf16x8 v; } bu;
#pragma unroll
        for (int j = 0; j < 8; ++j) {
            const int m = m0 + j;
            float val = 0.f;
            if (m < M_N) {
                float dx = metap[m * 3 + 0] - sx;
                float dy = metap[m * 3 + 1] - sy;
                float dz = metap[m * 3 + 2] - sz;
                float d = sqrtf(dx * dx + dy * dy + dz * dz);
                float amp = 1e-3f / (d * d);
                float r = coef * d * INV_TWO_PI;
                r -= floorf(r);
                float tr = isIm ? __builtin_amdgcn_sinf(r) : __builtin_amdgcn_cosf(r);
                val = amp * tr;
            }
            bu.u[j] = f2bf(val);
        }

        const ushort* wbase = Wbf + ((size_t)(f * NK + kb) * 48) * 32 + quad * 8;
        bf16x8 a0 = *(const bf16x8*)(wbase + (size_t)l16 * 32);
        bf16x8 a1 = *(const bf16x8*)(wbase + (size_t)(16 + l16) * 32);
        bf16x8 a2 = *(const bf16x8*)(wbase + (size_t)(32 + l16) * 32);
        acc0 = __builtin_amdgcn_mfma_f32_16x16x32_bf16(a0, bu.v, acc0, 0, 0, 0);
        acc1 = __builtin_amdgcn_mfma_f32_16x16x32_bf16(a1, bu.v, acc1, 0, 0, 0);
        acc2 = __builtin_amdgcn_mfma_f32_16x16x32_bf16(a2, bu.v, acc2, 0, 0, 0);
    }

    // C/D layout: col = lane&15, row = quad*4 + reg
    float* cb = Cp + ((size_t)(ksp * 5 + f) * 48) * 800;
#pragma unroll
    for (int i = 0; i < 4; ++i) {
        int row = quad * 4 + i;
        cb[(size_t)row * 800 + n]        = acc0[i];
        cb[(size_t)(16 + row) * 800 + n] = acc1[i];
        cb[(size_t)(32 + row) * 800 + n] = acc2[i];
    }
}

// Combine split-K partials + complex reassembly on the fly.
__device__ __forceinline__ void combineC(const float* __restrict__ Cp, int f, int row,
                                         int s, float* re, float* im) {
    float r = 0.f, i = 0.f;
#pragma unroll
    for (int p = 0; p < 4; ++p) {
        const float* c = Cp + ((size_t)(p * 5 + f) * 48) * 800;
        r += c[(size_t)row * 800 + s]       - c[(size_t)(22 + row) * 800 + 400 + s];
        i += c[(size_t)row * 800 + 400 + s] + c[(size_t)(22 + row) * 800 + s];
    }
    *re = r; *im = i;
}

#define SA_BLOCKS 750
__global__ __launch_bounds__(256) void epilogue2_kernel(
    const float* __restrict__ Cp, const float* __restrict__ T,
    float* __restrict__ out)
{
    __shared__ float cre[S_N], cim[S_N];
    __shared__ float pR[256], pI[256];
    const int tid = threadIdx.x;
    const int blk = blockIdx.x;

    if (blk < SA_BLOCKS) {
        int i = blk * 256 + tid;           // 750*256 == 192000
        int s = i % S_N; int rest = i / S_N;
        int k = rest % K_N; rest /= K_N;
        int f = rest % F_N; int r = rest / F_N;

        float ar, ai, br, bi;
        combineC(Cp, f, k, s, &ar, &ai);
        combineC(Cp, f, 6 + r, s, &br, &bi);
        float cr = ar * br - ai * bi;
        float ci = ar * bi + ai * br;

        int base = (r * F_N + f) * 72;
#pragma unroll
        for (int j = 0; j < 12; ++j) {
            int row = base + j * K_N + k;
            out[SA_BASE + (size_t)row * S_N + s] = cr;
            out[SA_BASE + (size_t)(5760 + row) * S_N + s] = ci;
        }
    } else {
        int bk = blk - SA_BLOCKS;          // 0..479
        int k = bk % K_N;
        int f = (bk / K_N) % F_N;
        int r = bk / (K_N * F_N);

        for (int s = tid; s < S_N; s += 256) {
            float ar, ai, br, bi;
            combineC(Cp, f, k, s, &ar, &ai);
            combineC(Cp, f, 6 + r, s, &br, &bi);
            cre[s] = ar * br - ai * bi;
            cim[s] = ar * bi + ai * br;
        }
        __syncthreads();

        const int b = tid & 127;
        const int hs = tid >> 7;
        float accR = 0.f, accI = 0.f;
        const int sBeg = hs * 200, sEnd = sBeg + 200;
#pragma unroll 4
        for (int s = sBeg; s < sEnd; ++s) {
            float tv = T[s * B_N + b];
            accR += cre[s] * tv;
            accI += cim[s] * tv;
        }
        pR[tid] = accR; pI[tid] = accI;
        __syncthreads();
        if (tid < 128) {
            accR = pR[tid] + pR[tid + 128];
            accI = pI[tid] + pI[tid + 128];
            int base = (r * F_N + f) * 72;
#pragma unroll
            for (int j = 0; j < 12; ++j) {
                int row = base + j * K_N + k;
                out[MIC_BASE + (size_t)row * B_N + b] = accR;
                out[MIC_BASE + (size_t)(5760 + row) * B_N + b] = accI;
            }
        }
    }
}

// ---------------- Fallback path (round-14, used if ws too small) ----------------
__global__ __launch_bounds__(256) void prep_kernel(
    const float* __restrict__ w, const float* __restrict__ meta_theta,
    const float* __restrict__ fin, const float* __restrict__ txp,
    const float* __restrict__ rxp, const float* __restrict__ metap,
    float* __restrict__ A1, float* __restrict__ H4p)
{
    __shared__ float pri[K_N * T_N * 2];
    __shared__ float txs[T_N * 3];
    __shared__ float rxs[R_N * 3];
    const int tid = threadIdx.x;
    const int f = blockIdx.x / 15;
    const int mblk = blockIdx.x % 15;

    if (tid < K_N * T_N) {
        float sv, cv; fast_sincos(w[f * (K_N * T_N) + tid], &sv, &cv);
        pri[tid * 2] = cv; pri[tid * 2 + 1] = sv;
    }
    if (tid >= 64 && tid < 64 + T_N * 3) txs[tid - 64] = txp[tid - 64];
    if (tid >= 128 && tid < 128 + R_N * 3) rxs[tid - 128] = rxp[tid - 128];
    __syncthreads();

    const int m = mblk * 256 + tid;
    if (m >= M_N) return;

    const float px = metap[m * 3 + 0];
    const float py = metap[m * 3 + 1];
    const float pz = metap[m * 3 + 2];
    const float coef = NEG_TWO_PI_OVER_C * fin[f];

    float th = meta_theta[m];
    th = fminf(fmaxf(th, -PI_F), CLIP_HI);
    float phs, phc; fast_sincos(th, &phs, &phc);

    float hre[T_N], him[T_N];
#pragma unroll
    for (int t = 0; t < T_N; ++t) {
        float dx = txs[t * 3 + 0] - px, dy = txs[t * 3 + 1] - py, dz = txs[t * 3 + 2] - pz;
        float d = sqrtf(dx * dx + dy * dy + dz * dz);
        float amp = 1e-3f / (d * d);
        float sv, cv; fast_sincos(coef * d, &sv, &cv);
        hre[t] = amp * cv; him[t] = amp * sv;
    }
    float* a1 = A1 + ((size_t)f * M_N + m) * (K_N * 2);
#pragma unroll
    for (int k = 0; k < K_N; ++k) {
        float ar = 0.f, ai = 0.f;
#pragma unroll
        for (int t = 0; t < T_N; ++t) {
            float pr = pri[(k * T_N + t) * 2], pim = pri[(k * T_N + t) * 2 + 1];
            ar += pr * hre[t] - pim * him[t];
            ai += pr * him[t] + pim * hre[t];
        }
        a1[k * 2]     = ar * phc - ai * phs;
        a1[k * 2 + 1] = ar * phs + ai * phc;
    }
    float* h4 = H4p + ((size_t)f * M_N + m) * (R_N * 2);
#pragma unroll
    for (int r = 0; r < R_N; ++r) {
        float dx = rxs[r * 3 + 0] - px, dy = rxs[r * 3 + 1] - py, dz = rxs[r * 3 + 2] - pz;
        float d = sqrtf(dx * dx + dy * dy + dz * dz);
        float amp = 1e-3f / (d * d);
        float sv, cv; fast_sincos(coef * d, &sv, &cv);
        float cr = amp * cv, ci = amp * sv;
        h4[r * 2]     = cr * phc - ci * phs;
        h4[r * 2 + 1] = cr * phs + ci * phc;
    }
}

__global__ __launch_bounds__(256, 2) void main_kernel(
    const float* __restrict__ fin, const float* __restrict__ metap,
    const float* __restrict__ scenep, const float* __restrict__ A1,
    const float* __restrict__ H4p, float* __restrict__ A2, float* __restrict__ Bm)
{
    const int f = blockIdx.x / 200;
    const int sq = blockIdx.x % 200;
    const int s0 = 2 * sq, s1 = s0 + 1;
    const int tid = threadIdx.x;

    const float coef = NEG_TWO_PI_OVER_C * fin[f];
    const float sx0 = scenep[s0 * 3], sy0 = scenep[s0 * 3 + 1], sz0 = scenep[s0 * 3 + 2];
    const float sx1 = scenep[s1 * 3], sy1 = scenep[s1 * 3 + 1], sz1 = scenep[s1 * 3 + 2];

    float acc[88];
#pragma unroll
    for (int i = 0; i < 88; ++i) acc[i] = 0.f;

    const float4* a1base = (const float4*)(A1 + (size_t)f * M_N * (K_N * 2));
    const float4* h4base = (const float4*)(H4p + (size_t)f * M_N * (R_N * 2));

    for (int m = tid; m < M_N; m += 256) {
        float px = metap[m * 3 + 0], py = metap[m * 3 + 1], pz = metap[m * 3 + 2];
        float dx0 = px - sx0, dy0 = py - sy0, dz0 = pz - sz0;
        float d0 = sqrtf(dx0 * dx0 + dy0 * dy0 + dz0 * dz0);
        float dx1 = px - sx1, dy1 = py - sy1, dz1 = pz - sz1;
        float d1 = sqrtf(dx1 * dx1 + dy1 * dy1 + dz1 * dz1);
        float sv0, cv0, sv1, cv1;
        fast_sincos(coef * d0, &sv0, &cv0);
        fast_sincos(coef * d1, &sv1, &cv1);
        float amp0 = 1e-3f / (d0 * d0), amp1 = 1e-3f / (d1 * d1);
        float h2r0 = amp0 * cv0, h2i0 = amp0 * sv0;
        float h2r1 = amp1 * cv1, h2i1 = amp1 * sv1;

        const float4* a1 = a1base + (size_t)m * 3;
#pragma unroll
        for (int q = 0; q < 3; ++q) {
            float4 v = a1[q];
            acc[4 * q + 0] += v.x * h2r0 - v.y * h2i0;
            acc[4 * q + 1] += v.x * h2i0 + v.y * h2r0;
            acc[4 * q + 2] += v.z * h2r0 - v.w * h2i0;
            acc[4 * q + 3] += v.z * h2i0 + v.w * h2r0;
            acc[44 + 4 * q + 0] += v.x * h2r1 - v.y * h2i1;
            acc[44 + 4 * q + 1] += v.x * h2i1 + v.y * h2r1;
            acc[44 + 4 * q + 2] += v.z * h2r1 - v.w * h2i1;
            acc[44 + 4 * q + 3] += v.z * h2i1 + v.w * h2r1;
        }
        const float4* h4 = h4base + (size_t)m * 8;
#pragma unroll
        for (int q = 0; q < 8; ++q) {
            float4 v = h4[q];
            acc[12 + 4 * q + 0] += v.x * h2r0 - v.y * h2i0;
            acc[12 + 4 * q + 1] += v.x * h2i0 + v.y * h2r0;
            acc[12 + 4 * q + 2] += v.z * h2r0 - v.w * h2i0;
            acc[12 + 4 * q + 3] += v.z * h2i0 + v.w * h2r0;
            acc[56 + 4 * q + 0] += v.x * h2r1 - v.y * h2i1;
            acc[56 + 4 * q + 1] += v.x * h2i1 + v.y * h2r1;
            acc[56 + 4 * q + 2] += v.z * h2r1 - v.w * h2i1;
            acc[56 + 4 * q + 3] += v.z * h2i1 + v.w * h2r1;
        }
    }

#pragma unroll
    for (int off = 32; off > 0; off >>= 1) {
#pragma unroll
        for (int i = 0; i < 88; ++i) acc[i] += __shfl_down(acc[i], off);
    }
    __shared__ float red[4][88];
    const int wave = tid >> 6, lane = tid & 63;
    if (lane == 0) {
#pragma unroll
        for (int i = 0; i < 88; ++i) red[wave][i] = acc[i];
    }
    __syncthreads();
    if (tid < 88) {
        float v = red[0][tid] + red[1][tid] + red[2][tid] + red[3][tid];
        int half = tid / 44, slot = tid - 44 * half;
        int s = half ? s1 : s0;
        if (slot < 12) {
            int k = slot >> 1, c = slot & 1;
            A2[(((size_t)f * K_N + k) * S_N + s) * 2 + c] = v;
        } else {
            int j = slot - 12; int r = j >> 1, c = j & 1;
            Bm[(((size_t)f * S_N + s) * R_N + r) * 2 + c] = v;
        }
    }
}

__global__ __launch_bounds__(256) void epilogue_kernel(
    const float* __restrict__ A2, const float* __restrict__ Bm,
    const float* __restrict__ T, float* __restrict__ out)
{
    __shared__ float cre[S_N], cim[S_N];
    __shared__ float pR[256], pI[256];
    const int tid = threadIdx.x;
    const int blk = blockIdx.x;

    if (blk < SA_BLOCKS) {
        int i = blk * 256 + tid;
        int s = i % S_N; int rest = i / S_N;
        int k = rest % K_N; rest /= K_N;
        int f = rest % F_N; int r = rest / F_N;

        float ar = A2[((f * K_N + k) * S_N + s) * 2];
        float ai = A2[((f * K_N + k) * S_N + s) * 2 + 1];
        float br = Bm[((f * S_N + s) * R_N + r) * 2];
        float bi = Bm[((f * S_N + s) * R_N + r) * 2 + 1];
        float cr = ar * br - ai * bi;
        float ci = ar * bi + ai * br;

        int base = (r * F_N + f) * 72;
#pragma unroll
        for (int j = 0; j < 12; ++j) {
            int row = base + j * K_N + k;
            out[SA_BASE + (size_t)row * S_N + s] = cr;
            out[SA_BASE + (size_t)(5760 + row) * S_N + s] = ci;
        }
    } else {
        int bk = blk - SA_BLOCKS;
        int k = bk % K_N;
        int f = (bk / K_N) % F_N;
        int r = bk / (K_N * F_N);

        for (int s = tid; s < S_N; s += 256) {
            float ar = A2[((f * K_N + k) * S_N + s) * 2];
            float ai = A2[((f * K_N + k) * S_N + s) * 2 + 1];
            float br = Bm[((f * S_N + s) * R_N + r) * 2];
            float bi = Bm[((f * S_N + s) * R_N + r) * 2 + 1];
            cre[s] = ar * br - ai * bi;
            cim[s] = ar * bi + ai * br;
        }
        __syncthreads();

        const int b = tid & 127;
        const int hs = tid >> 7;
        float accR = 0.f, accI = 0.f;
        const int sBeg = hs * 200, sEnd = sBeg + 200;
#pragma unroll 4
        for (int s = sBeg; s < sEnd; ++s) {
            float tv = T[s * B_N + b];
            accR += cre[s] * tv;
            accI += cim[s] * tv;
        }
        pR[tid] = accR; pI[tid] = accI;
        __syncthreads();
        if (tid < 128) {
            accR = pR[tid] + pR[tid + 128];
            accI = pI[tid] + pI[tid + 128];
            int base = (r * F_N + f) * 72;
#pragma unroll
            for (int j = 0; j < 12; ++j) {
                int row = base + j * K_N + k;
                out[MIC_BASE + (size_t)row * B_N + b] = accR;
                out[MIC_BASE + (size_t)(5760 + row) * B_N + b] = accI;
            }
        }
    }
}

extern "C" void kernel_launch(void* const* d_in, const int* in_sizes, int n_in,
                              void* d_out, int out_size, void* d_ws, size_t ws_size,
                              hipStream_t stream) {
    const float* T  = (const float*)d_in[0];
    const float* w  = (const float*)d_in[1];
    const float* th = (const float*)d_in[2];
    const float* fr = (const float*)d_in[3];
    const float* tx = (const float*)d_in[4];
    const float* rx = (const float*)d_in[5];
    const float* mp = (const float*)d_in[6];
    const float* sp = (const float*)d_in[7];

    float* out = (float*)d_out;

    if (ws_size >= WS_NEED) {
        __hip_bfloat16* Wbf = (__hip_bfloat16*)d_ws;
        float* Cp = (float*)((char*)d_ws + (size_t)W_ELEMS * 2);

        stage_kernel<<<75, 256, 0, stream>>>(w, th, fr, tx, rx, mp, Wbf);
        gemm_kernel<<<500, 128, 0, stream>>>((const ushort*)Wbf, fr, mp, sp, Cp);
        epilogue2_kernel<<<SA_BLOCKS + 480, 256, 0, stream>>>(Cp, T, out);
    } else {
        float* ws  = (float*)d_ws;
        float* A1  = ws;
        float* H4p = ws + 216000;
        float* A2  = ws + 792000;
        float* Bm  = ws + 816000;

        prep_kernel<<<75, 256, 0, stream>>>(w, th, fr, tx, rx, mp, A1, H4p);
        main_kernel<<<F_N * 200, 256, 0, stream>>>(fr, mp, sp, A1, H4p, A2, Bm);
        epilogue_kernel<<<SA_BLOCKS + 480, 256, 0, stream>>>(A2, Bm, T, out);
    }
}

// Round 18
// 122.512 us; speedup vs baseline: 1.3411x; 1.3411x over previous
//
#include <hip/hip_runtime.h>
#include <hip/hip_bf16.h>
#include <math.h>

#define F_N 5
#define K_N 6
#define T_N 12
#define M_N 3600
#define S_N 400
#define R_N 16
#define B_N 128

#define PI_F 3.14159265358979f
#define CLIP_HI 0.3490658503988659f
#define NEG_TWO_PI_OVER_C (-6.283185307179586f / 3.0e8f)
#define INV_TWO_PI 0.15915494309189535f

#define SA_BASE   0         // s_A  [11520][400] float32
#define MIC_BASE  4608000   // s_mic [11520][128] float32

#define NK 113              // K-chunks of 32 (113*32 = 3616 >= 3600)
#define KP (NK * 32)
#define W_ELEMS  (5 * 48 * KP)        // 867,840 bf16   W2[f][kk][48][32]
#define H_ELEMS  (5 * 800 * KP)       // 14,464,000 bf16 H2[f][kk][800][32]
#define C_ELEMS  (4 * 5 * 48 * 800)   // 768,000 f32 (split-K=4 partials)
#define WS_NEED  ((size_t)(W_ELEMS + H_ELEMS) * 2 + (size_t)C_ELEMS * 4)

typedef __attribute__((ext_vector_type(8))) short bf16x8;
typedef __attribute__((ext_vector_type(4))) float f32x4;

// Hardware sin/cos (v_sin_f32/v_cos_f32 take REVOLUTIONS; fract first).
__device__ __forceinline__ void fast_sincos(float x, float* s, float* c) {
    float r = x * INV_TWO_PI;
    r -= floorf(r);
    *s = __builtin_amdgcn_sinf(r);
    *c = __builtin_amdgcn_cosf(r);
}

// ---------------- MFMA path (round-16 structure: H materialized) ----------------
// W2[f][kk][row48][32]  row: 0..5 Re(A1 k), 6..21 Re(H4p r),
//                            22..27 Im(A1 k), 28..43 Im(H4p r), 44..47 zero
// H2[f][kk][n800][32]   n: 0..399 Re(H2[:,s]), 400..799 Im(H2[:,s])
// NOTE (round 17 lesson): do NOT fuse H-generation into gemm — gemm has only
// ~1 wave/SIMD and the sincos chain serializes (67.6 us vs ~5 us when staged
// by the 2000-block kernel below).

__global__ __launch_bounds__(256) void stage_kernel(
    const float* __restrict__ w, const float* __restrict__ meta_theta,
    const float* __restrict__ fin, const float* __restrict__ txp,
    const float* __restrict__ rxp, const float* __restrict__ metap,
    const float* __restrict__ scenep,
    __hip_bfloat16* __restrict__ Wbf, __hip_bfloat16* __restrict__ Hbf)
{
    const int tid = threadIdx.x;
    const int blk = blockIdx.x;

    if (blk < 75) {                       // ---- W-pack ----
        __shared__ float pri[K_N * T_N * 2];
        __shared__ float txs[T_N * 3];
        __shared__ float rxs[R_N * 3];
        const int f = blk / 15;
        const int mblk = blk % 15;

        if (tid < K_N * T_N) {
            float sv, cv; fast_sincos(w[f * (K_N * T_N) + tid], &sv, &cv);
            pri[tid * 2] = cv; pri[tid * 2 + 1] = sv;
        }
        if (tid >= 64 && tid < 64 + T_N * 3) txs[tid - 64] = txp[tid - 64];
        if (tid >= 128 && tid < 128 + R_N * 3) rxs[tid - 128] = rxp[tid - 128];
        __syncthreads();

        const int m = mblk * 256 + tid;
        if (m >= KP) return;
        __hip_bfloat16* wb = Wbf + ((size_t)(f * NK + (m >> 5)) * 48) * 32 + (m & 31);

        if (m >= M_N) {                   // K padding columns
            for (int row = 0; row < 48; ++row) wb[row * 32] = __float2bfloat16(0.f);
            return;
        }

        const float px = metap[m * 3 + 0];
        const float py = metap[m * 3 + 1];
        const float pz = metap[m * 3 + 2];
        const float coef = NEG_TWO_PI_OVER_C * fin[f];

        float th = meta_theta[m];
        th = fminf(fmaxf(th, -PI_F), CLIP_HI);
        float phs, phc; fast_sincos(th, &phs, &phc);

        float hre[T_N], him[T_N];
#pragma unroll
        for (int t = 0; t < T_N; ++t) {
            float dx = txs[t * 3 + 0] - px, dy = txs[t * 3 + 1] - py, dz = txs[t * 3 + 2] - pz;
            float d = sqrtf(dx * dx + dy * dy + dz * dz);
            float amp = 1e-3f / (d * d);
            float sv, cv; fast_sincos(coef * d, &sv, &cv);
            hre[t] = amp * cv; him[t] = amp * sv;
        }
#pragma unroll
        for (int k = 0; k < K_N; ++k) {
            float ar = 0.f, ai = 0.f;
#pragma unroll
            for (int t = 0; t < T_N; ++t) {
                float pr = pri[(k * T_N + t) * 2], pim = pri[(k * T_N + t) * 2 + 1];
                ar += pr * hre[t] - pim * him[t];
                ai += pr * him[t] + pim * hre[t];
            }
            wb[k * 32]        = __float2bfloat16(ar * phc - ai * phs);
            wb[(22 + k) * 32] = __float2bfloat16(ar * phs + ai * phc);
        }
#pragma unroll
        for (int r = 0; r < R_N; ++r) {
            float dx = rxs[r * 3 + 0] - px, dy = rxs[r * 3 + 1] - py, dz = rxs[r * 3 + 2] - pz;
            float d = sqrtf(dx * dx + dy * dy + dz * dz);
            float amp = 1e-3f / (d * d);
            float sv, cv; fast_sincos(coef * d, &sv, &cv);
            float cr = amp * cv, ci = amp * sv;
            wb[(6 + r) * 32]  = __float2bfloat16(cr * phc - ci * phs);
            wb[(28 + r) * 32] = __float2bfloat16(cr * phs + ci * phc);
        }
#pragma unroll
        for (int row = 44; row < 48; ++row) wb[row * 32] = __float2bfloat16(0.f);
    } else {                              // ---- H2 generation ----
        const int q = blk - 75;           // 0..1999
        const int f = q / S_N;
        const int s = q % S_N;
        const float coef = NEG_TWO_PI_OVER_C * fin[f];
        const float sx = scenep[s * 3 + 0];
        const float sy = scenep[s * 3 + 1];
        const float sz = scenep[s * 3 + 2];

        for (int m = tid; m < KP; m += 256) {
            float re = 0.f, im = 0.f;
            if (m < M_N) {
                float px = metap[m * 3 + 0], py = metap[m * 3 + 1], pz = metap[m * 3 + 2];
                float dx = px - sx, dy = py - sy, dz = pz - sz;
                float d = sqrtf(dx * dx + dy * dy + dz * dz);
                float amp = 1e-3f / (d * d);
                float sv, cv; fast_sincos(coef * d, &sv, &cv);
                re = amp * cv; im = amp * sv;
            }
            size_t idx = ((size_t)(f * NK + (m >> 5)) * 800 + s) * 32 + (m & 31);
            Hbf[idx] = __float2bfloat16(re);
            Hbf[idx + 400 * 32] = __float2bfloat16(im);
        }
    }
}

// [48 x KP] x [KP x 800] bf16 MFMA GEMM per f, split-K=4 partials.
// Block = 128 thr (2 waves); wave owns N-tile of 16, all 3 M-tiles.
// All loads are contiguous 1KB per instruction (interleaved layout).
__global__ __launch_bounds__(128) void gemm_kernel(
    const ushort* __restrict__ Wbf, const ushort* __restrict__ Hbf,
    float* __restrict__ Cp)
{
    const int blk = blockIdx.x;           // 5 * 25 * 4 = 500
    const int f = blk / 100;
    const int rem = blk % 100;
    const int nblk = rem / 4;
    const int ksp = rem % 4;
    const int wave = threadIdx.x >> 6;
    const int lane = threadIdx.x & 63;
    const int quad = lane >> 4;
    const int l16 = lane & 15;

    const int n = nblk * 32 + wave * 16 + l16;      // < 800
    const int kbeg = (ksp == 0) ? 0 : (29 + 28 * (ksp - 1));
    const int kcnt = (ksp == 0) ? 29 : 28;          // 29+28*3 == 113

    f32x4 acc0 = {0.f, 0.f, 0.f, 0.f};
    f32x4 acc1 = {0.f, 0.f, 0.f, 0.f};
    f32x4 acc2 = {0.f, 0.f, 0.f, 0.f};

    for (int kk = 0; kk < kcnt; ++kk) {
        const int kb = kbeg + kk;
        bf16x8 b  = *(const bf16x8*)(Hbf + ((size_t)(f * NK + kb) * 800 + n) * 32 + quad * 8);
        const ushort* wbase = Wbf + ((size_t)(f * NK + kb) * 48) * 32 + quad * 8;
        bf16x8 a0 = *(const bf16x8*)(wbase + (size_t)l16 * 32);
        bf16x8 a1 = *(const bf16x8*)(wbase + (size_t)(16 + l16) * 32);
        bf16x8 a2 = *(const bf16x8*)(wbase + (size_t)(32 + l16) * 32);
        acc0 = __builtin_amdgcn_mfma_f32_16x16x32_bf16(a0, b, acc0, 0, 0, 0);
        acc1 = __builtin_amdgcn_mfma_f32_16x16x32_bf16(a1, b, acc1, 0, 0, 0);
        acc2 = __builtin_amdgcn_mfma_f32_16x16x32_bf16(a2, b, acc2, 0, 0, 0);
    }

    // C/D layout: col = lane&15, row = quad*4 + reg
    float* cb = Cp + ((size_t)(ksp * 5 + f) * 48) * 800;
#pragma unroll
    for (int i = 0; i < 4; ++i) {
        int row = quad * 4 + i;
        cb[(size_t)row * 800 + n]        = acc0[i];
        cb[(size_t)(16 + row) * 800 + n] = acc1[i];
        cb[(size_t)(32 + row) * 800 + n] = acc2[i];
    }
}

// Combine split-K partials + complex reassembly on the fly.
__device__ __forceinline__ void combineC(const float* __restrict__ Cp, int f, int row,
                                         int s, float* re, float* im) {
    float r = 0.f, i = 0.f;
#pragma unroll
    for (int p = 0; p < 4; ++p) {
        const float* c = Cp + ((size_t)(p * 5 + f) * 48) * 800;
        r += c[(size_t)row * 800 + s]       - c[(size_t)(22 + row) * 800 + 400 + s];
        i += c[(size_t)row * 800 + 400 + s] + c[(size_t)(22 + row) * 800 + s];
    }
    *re = r; *im = i;
}

#define SA_BLOCKS 750
__global__ __launch_bounds__(256) void epilogue2_kernel(
    const float* __restrict__ Cp, const float* __restrict__ T,
    float* __restrict__ out)
{
    __shared__ float cre[S_N], cim[S_N];
    __shared__ float pR[256], pI[256];
    const int tid = threadIdx.x;
    const int blk = blockIdx.x;

    if (blk < SA_BLOCKS) {
        int i = blk * 256 + tid;           // 750*256 == 192000
        int s = i % S_N; int rest = i / S_N;
        int k = rest % K_N; rest /= K_N;
        int f = rest % F_N; int r = rest / F_N;

        float ar, ai, br, bi;
        combineC(Cp, f, k, s, &ar, &ai);
        combineC(Cp, f, 6 + r, s, &br, &bi);
        float cr = ar * br - ai * bi;
        float ci = ar * bi + ai * br;

        int base = (r * F_N + f) * 72;
#pragma unroll
        for (int j = 0; j < 12; ++j) {
            int row = base + j * K_N + k;
            out[SA_BASE + (size_t)row * S_N + s] = cr;
            out[SA_BASE + (size_t)(5760 + row) * S_N + s] = ci;
        }
    } else {
        int bk = blk - SA_BLOCKS;          // 0..479
        int k = bk % K_N;
        int f = (bk / K_N) % F_N;
        int r = bk / (K_N * F_N);

        for (int s = tid; s < S_N; s += 256) {
            float ar, ai, br, bi;
            combineC(Cp, f, k, s, &ar, &ai);
            combineC(Cp, f, 6 + r, s, &br, &bi);
            cre[s] = ar * br - ai * bi;
            cim[s] = ar * bi + ai * br;
        }
        __syncthreads();

        const int b = tid & 127;
        const int hs = tid >> 7;
        float accR = 0.f, accI = 0.f;
        const int sBeg = hs * 200, sEnd = sBeg + 200;
#pragma unroll 4
        for (int s = sBeg; s < sEnd; ++s) {
            float tv = T[s * B_N + b];
            accR += cre[s] * tv;
            accI += cim[s] * tv;
        }
        pR[tid] = accR; pI[tid] = accI;
        __syncthreads();
        if (tid < 128) {
            accR = pR[tid] + pR[tid + 128];
            accI = pI[tid] + pI[tid + 128];
            int base = (r * F_N + f) * 72;
#pragma unroll
            for (int j = 0; j < 12; ++j) {
                int row = base + j * K_N + k;
                out[MIC_BASE + (size_t)row * B_N + b] = accR;
                out[MIC_BASE + (size_t)(5760 + row) * B_N + b] = accI;
            }
        }
    }
}

// ---------------- Fallback path (round-14, used if ws too small) ----------------
__global__ __launch_bounds__(256) void prep_kernel(
    const float* __restrict__ w, const float* __restrict__ meta_theta,
    const float* __restrict__ fin, const float* __restrict__ txp,
    const float* __restrict__ rxp, const float* __restrict__ metap,
    float* __restrict__ A1, float* __restrict__ H4p)
{
    __shared__ float pri[K_N * T_N * 2];
    __shared__ float txs[T_N * 3];
    __shared__ float rxs[R_N * 3];
    const int tid = threadIdx.x;
    const int f = blockIdx.x / 15;
    const int mblk = blockIdx.x % 15;

    if (tid < K_N * T_N) {
        float sv, cv; fast_sincos(w[f * (K_N * T_N) + tid], &sv, &cv);
        pri[tid * 2] = cv; pri[tid * 2 + 1] = sv;
    }
    if (tid >= 64 && tid < 64 + T_N * 3) txs[tid - 64] = txp[tid - 64];
    if (tid >= 128 && tid < 128 + R_N * 3) rxs[tid - 128] = rxp[tid - 128];
    __syncthreads();

    const int m = mblk * 256 + tid;
    if (m >= M_N) return;

    const float px = metap[m * 3 + 0];
    const float py = metap[m * 3 + 1];
    const float pz = metap[m * 3 + 2];
    const float coef = NEG_TWO_PI_OVER_C * fin[f];

    float th = meta_theta[m];
    th = fminf(fmaxf(th, -PI_F), CLIP_HI);
    float phs, phc; fast_sincos(th, &phs, &phc);

    float hre[T_N], him[T_N];
#pragma unroll
    for (int t = 0; t < T_N; ++t) {
        float dx = txs[t * 3 + 0] - px, dy = txs[t * 3 + 1] - py, dz = txs[t * 3 + 2] - pz;
        float d = sqrtf(dx * dx + dy * dy + dz * dz);
        float amp = 1e-3f / (d * d);
        float sv, cv; fast_sincos(coef * d, &sv, &cv);
        hre[t] = amp * cv; him[t] = amp * sv;
    }
    float* a1 = A1 + ((size_t)f * M_N + m) * (K_N * 2);
#pragma unroll
    for (int k = 0; k < K_N; ++k) {
        float ar = 0.f, ai = 0.f;
#pragma unroll
        for (int t = 0; t < T_N; ++t) {
            float pr = pri[(k * T_N + t) * 2], pim = pri[(k * T_N + t) * 2 + 1];
            ar += pr * hre[t] - pim * him[t];
            ai += pr * him[t] + pim * hre[t];
        }
        a1[k * 2]     = ar * phc - ai * phs;
        a1[k * 2 + 1] = ar * phs + ai * phc;
    }
    float* h4 = H4p + ((size_t)f * M_N + m) * (R_N * 2);
#pragma unroll
    for (int r = 0; r < R_N; ++r) {
        float dx = rxs[r * 3 + 0] - px, dy = rxs[r * 3 + 1] - py, dz = rxs[r * 3 + 2] - pz;
        float d = sqrtf(dx * dx + dy * dy + dz * dz);
        float amp = 1e-3f / (d * d);
        float sv, cv; fast_sincos(coef * d, &sv, &cv);
        float cr = amp * cv, ci = amp * sv;
        h4[r * 2]     = cr * phc - ci * phs;
        h4[r * 2 + 1] = cr * phs + ci * phc;
    }
}

__global__ __launch_bounds__(256, 2) void main_kernel(
    const float* __restrict__ fin, const float* __restrict__ metap,
    const float* __restrict__ scenep, const float* __restrict__ A1,
    const float* __restrict__ H4p, float* __restrict__ A2, float* __restrict__ Bm)
{
    const int f = blockIdx.x / 200;
    const int sq = blockIdx.x % 200;
    const int s0 = 2 * sq, s1 = s0 + 1;
    const int tid = threadIdx.x;

    const float coef = NEG_TWO_PI_OVER_C * fin[f];
    const float sx0 = scenep[s0 * 3], sy0 = scenep[s0 * 3 + 1], sz0 = scenep[s0 * 3 + 2];
    const float sx1 = scenep[s1 * 3], sy1 = scenep[s1 * 3 + 1], sz1 = scenep[s1 * 3 + 2];

    float acc[88];
#pragma unroll
    for (int i = 0; i < 88; ++i) acc[i] = 0.f;

    const float4* a1base = (const float4*)(A1 + (size_t)f * M_N * (K_N * 2));
    const float4* h4base = (const float4*)(H4p + (size_t)f * M_N * (R_N * 2));

    for (int m = tid; m < M_N; m += 256) {
        float px = metap[m * 3 + 0], py = metap[m * 3 + 1], pz = metap[m * 3 + 2];
        float dx0 = px - sx0, dy0 = py - sy0, dz0 = pz - sz0;
        float d0 = sqrtf(dx0 * dx0 + dy0 * dy0 + dz0 * dz0);
        float dx1 = px - sx1, dy1 = py - sy1, dz1 = pz - sz1;
        float d1 = sqrtf(dx1 * dx1 + dy1 * dy1 + dz1 * dz1);
        float sv0, cv0, sv1, cv1;
        fast_sincos(coef * d0, &sv0, &cv0);
        fast_sincos(coef * d1, &sv1, &cv1);
        float amp0 = 1e-3f / (d0 * d0), amp1 = 1e-3f / (d1 * d1);
        float h2r0 = amp0 * cv0, h2i0 = amp0 * sv0;
        float h2r1 = amp1 * cv1, h2i1 = amp1 * sv1;

        const float4* a1 = a1base + (size_t)m * 3;
#pragma unroll
        for (int q = 0; q < 3; ++q) {
            float4 v = a1[q];
            acc[4 * q + 0] += v.x * h2r0 - v.y * h2i0;
            acc[4 * q + 1] += v.x * h2i0 + v.y * h2r0;
            acc[4 * q + 2] += v.z * h2r0 - v.w * h2i0;
            acc[4 * q + 3] += v.z * h2i0 + v.w * h2r0;
            acc[44 + 4 * q + 0] += v.x * h2r1 - v.y * h2i1;
            acc[44 + 4 * q + 1] += v.x * h2i1 + v.y * h2r1;
            acc[44 + 4 * q + 2] += v.z * h2r1 - v.w * h2i1;
            acc[44 + 4 * q + 3] += v.z * h2i1 + v.w * h2r1;
        }
        const float4* h4 = h4base + (size_t)m * 8;
#pragma unroll
        for (int q = 0; q < 8; ++q) {
            float4 v = h4[q];
            acc[12 + 4 * q + 0] += v.x * h2r0 - v.y * h2i0;
            acc[12 + 4 * q + 1] += v.x * h2i0 + v.y * h2r0;
            acc[12 + 4 * q + 2] += v.z * h2r0 - v.w * h2i0;
            acc[12 + 4 * q + 3] += v.z * h2i0 + v.w * h2r0;
            acc[56 + 4 * q + 0] += v.x * h2r1 - v.y * h2i1;
            acc[56 + 4 * q + 1] += v.x * h2i1 + v.y * h2r1;
            acc[56 + 4 * q + 2] += v.z * h2r1 - v.w * h2i1;
            acc[56 + 4 * q + 3] += v.z * h2i1 + v.w * h2r1;
        }
    }

#pragma unroll
    for (int off = 32; off > 0; off >>= 1) {
#pragma unroll
        for (int i = 0; i < 88; ++i) acc[i] += __shfl_down(acc[i], off);
    }
    __shared__ float red[4][88];
    const int wave = tid >> 6, lane = tid & 63;
    if (lane == 0) {
#pragma unroll
        for (int i = 0; i < 88; ++i) red[wave][i] = acc[i];
    }
    __syncthreads();
    if (tid < 88) {
        float v = red[0][tid] + red[1][tid] + red[2][tid] + red[3][tid];
        int half = tid / 44, slot = tid - 44 * half;
        int s = half ? s1 : s0;
        if (slot < 12) {
            int k = slot >> 1, c = slot & 1;
            A2[(((size_t)f * K_N + k) * S_N + s) * 2 + c] = v;
        } else {
            int j = slot - 12; int r = j >> 1, c = j & 1;
            Bm[(((size_t)f * S_N + s) * R_N + r) * 2 + c] = v;
        }
    }
}

__global__ __launch_bounds__(256) void epilogue_kernel(
    const float* __restrict__ A2, const float* __restrict__ Bm,
    const float* __restrict__ T, float* __restrict__ out)
{
    __shared__ float cre[S_N], cim[S_N];
    __shared__ float pR[256], pI[256];
    const int tid = threadIdx.x;
    const int blk = blockIdx.x;

    if (blk < SA_BLOCKS) {
        int i = blk * 256 + tid;
        int s = i % S_N; int rest = i / S_N;
        int k = rest % K_N; rest /= K_N;
        int f = rest % F_N; int r = rest / F_N;

        float ar = A2[((f * K_N + k) * S_N + s) * 2];
        float ai = A2[((f * K_N + k) * S_N + s) * 2 + 1];
        float br = Bm[((f * S_N + s) * R_N + r) * 2];
        float bi = Bm[((f * S_N + s) * R_N + r) * 2 + 1];
        float cr = ar * br - ai * bi;
        float ci = ar * bi + ai * br;

        int base = (r * F_N + f) * 72;
#pragma unroll
        for (int j = 0; j < 12; ++j) {
            int row = base + j * K_N + k;
            out[SA_BASE + (size_t)row * S_N + s] = cr;
            out[SA_BASE + (size_t)(5760 + row) * S_N + s] = ci;
        }
    } else {
        int bk = blk - SA_BLOCKS;
        int k = bk % K_N;
        int f = (bk / K_N) % F_N;
        int r = bk / (K_N * F_N);

        for (int s = tid; s < S_N; s += 256) {
            float ar = A2[((f * K_N + k) * S_N + s) * 2];
            float ai = A2[((f * K_N + k) * S_N + s) * 2 + 1];
            float br = Bm[((f * S_N + s) * R_N + r) * 2];
            float bi = Bm[((f * S_N + s) * R_N + r) * 2 + 1];
            cre[s] = ar * br - ai * bi;
            cim[s] = ar * bi + ai * br;
        }
        __syncthreads();

        const int b = tid & 127;
        const int hs = tid >> 7;
        float accR = 0.f, accI = 0.f;
        const int sBeg = hs * 200, sEnd = sBeg + 200;
#pragma unroll 4
        for (int s = sBeg; s < sEnd; ++s) {
            float tv = T[s * B_N + b];
            accR += cre[s] * tv;
            accI += cim[s] * tv;
        }
        pR[tid] = accR; pI[tid] = accI;
        __syncthreads();
        if (tid < 128) {
            accR = pR[tid] + pR[tid + 128];
            accI = pI[tid] + pI[tid + 128];
            int base = (r * F_N + f) * 72;
#pragma unroll
            for (int j = 0; j < 12; ++j) {
                int row = base + j * K_N + k;
                out[MIC_BASE + (size_t)row * B_N + b] = accR;
                out[MIC_BASE + (size_t)(5760 + row) * B_N + b] = accI;
            }
        }
    }
}

extern "C" void kernel_launch(void* const* d_in, const int* in_sizes, int n_in,
                              void* d_out, int out_size, void* d_ws, size_t ws_size,
                              hipStream_t stream) {
    const float* T  = (const float*)d_in[0];
    const float* w  = (const float*)d_in[1];
    const float* th = (const float*)d_in[2];
    const float* fr = (const float*)d_in[3];
    const float* tx = (const float*)d_in[4];
    const float* rx = (const float*)d_in[5];
    const float* mp = (const float*)d_in[6];
    const float* sp = (const float*)d_in[7];

    float* out = (float*)d_out;

    if (ws_size >= WS_NEED) {
        __hip_bfloat16* Wbf = (__hip_bfloat16*)d_ws;
        __hip_bfloat16* Hbf = Wbf + W_ELEMS;
        float* Cp = (float*)(Hbf + H_ELEMS);

        stage_kernel<<<75 + 2000, 256, 0, stream>>>(w, th, fr, tx, rx, mp, sp, Wbf, Hbf);
        gemm_kernel<<<500, 128, 0, stream>>>((const ushort*)Wbf, (const ushort*)Hbf, Cp);
        epilogue2_kernel<<<SA_BLOCKS + 480, 256, 0, stream>>>(Cp, T, out);
    } else {
        float* ws  = (float*)d_ws;
        float* A1  = ws;
        float* H4p = ws + 216000;
        float* A2  = ws + 792000;
        float* Bm  = ws + 816000;

        prep_kernel<<<75, 256, 0, stream>>>(w, th, fr, tx, rx, mp, A1, H4p);
        main_kernel<<<F_N * 200, 256, 0, stream>>>(fr, mp, sp, A1, H4p, A2, Bm);
        epilogue_kernel<<<SA_BLOCKS + 480, 256, 0, stream>>>(A2, Bm, T, out);
    }
}